// Round 2
// baseline (90.301 us; speedup 1.0000x reference)
//
#include <hip/hip_runtime.h>

// RoiPoolingConv: crop_and_resize (bilinear, 14x14 grid) + 2x2 max pool
// fm: (38,50,512) f32; rois: (512,5) f32 [batch, x1, y1, x2, y2]
// out[n,ph,pw,c] = max over (jy,ix in {0,1}) of bilinear sample (2ph+jy, 2pw+ix)
//
// R8 = R7's structure (one block per (n,ph), y-row dedup via NR template,
// amortized ROI decode) but with the x-loop made BRANCH-FREE and load-
// independent: per pw we always load 4 columns x NR rows. Duplicate columns
// (samples sharing a bilinear cell) are same-line L1 hits. All addresses are
// pure ALU of block-uniform ROI scalars -> no loop-carried deps, no
// data-dependent branches -> compiler can hoist/pipeline loads across the
// fully-unrolled pw loop (R7's sliding window serialized on vmcnt each step).

#define FM_H 38
#define FM_W 50
#define NCH  512

typedef float v4f __attribute__((ext_vector_type(4)));

__device__ __forceinline__ float4 lerp4(const float4 a, const float4 b, const float w) {
    const float iw = 1.0f - w;
    return make_float4(a.x * iw + b.x * w,
                       a.y * iw + b.y * w,
                       a.z * iw + b.z * w,
                       a.w * iw + b.w * w);
}

__device__ __forceinline__ float4 max4(const float4 a, const float4 b) {
    return make_float4(fmaxf(a.x, b.x), fmaxf(a.y, b.y),
                       fmaxf(a.z, b.z), fmaxf(a.w, b.w));
}

#define LD4(p) (*(const float4*)(p))

__device__ __forceinline__ void st_nt4(float* p, const float4 v) {
    v4f vv;
    vv.x = v.x; vv.y = v.y; vv.z = v.z; vv.w = v.w;
    __builtin_nontemporal_store(vv, (v4f*)p);
}

// NR = number of distinct fm rows (2: same cell, 3: adjacent, 4: disjoint).
// y-sample 0 (weight wy0) interpolates rows d[0],d[1];
// y-sample 1 (weight wy1) interpolates rows d[NR-2],d[NR-1].
template<int NR>
__device__ __forceinline__ void roi_rows(const float* rp0, const float* rp1,
                                         const float* rp2, const float* rp3,
                                         const float wy0, const float wy1,
                                         const float x1, const float dx,
                                         float* __restrict__ outp)
{
    const float SX = 49.0f / 800.0f;    // (W-1)/IM_W
    const float* rp[4] = {rp0, rp1, rp2, rp3};

    #pragma unroll
    for (int pw = 0; pw < 7; ++pw) {
        // x samples i0 = 2*pw, i1 = 2*pw+1 — pure ALU, no deps on loads
        const float t0  = (float)(2 * pw)     * (1.0f / 13.0f);
        const float t1  = (float)(2 * pw + 1) * (1.0f / 13.0f);
        const float xx0 = (x1 + t0 * dx) * SX;
        const float xx1 = (x1 + t1 * dx) * SX;
        const float xf0 = floorf(xx0), xf1 = floorf(xx1);
        const float wx0 = xx0 - xf0;       // weights from UNclipped floor
        const float wx1 = xx1 - xf1;
        int a0 = (int)xf0; a0 = min(max(a0, 0), FM_W - 1);
        int a1 = (int)xf1; a1 = min(max(a1, 0), FM_W - 1);
        const int b0 = min(a0 + 1, FM_W - 1);
        const int b1 = min(a1 + 1, FM_W - 1);
        const int oA0 = a0 * NCH, oB0 = b0 * NCH;
        const int oA1 = a1 * NCH, oB1 = b1 * NCH;

        // Branch-free: always 4 columns per row. Duplicates (a1==a0 or
        // a1==b0) re-read the same cache line — L1 hit, no extra traffic.
        float4 v0[NR], v1[NR], v2[NR], v3[NR];
        #pragma unroll
        for (int r = 0; r < NR; ++r) {
            v0[r] = LD4(rp[r] + oA0);
            v1[r] = LD4(rp[r] + oB0);
            v2[r] = LD4(rp[r] + oA1);
            v3[r] = LD4(rp[r] + oB1);
        }

        float4 d0[NR], d1[NR];
        #pragma unroll
        for (int r = 0; r < NR; ++r) {
            d0[r] = lerp4(v0[r], v1[r], wx0);
            d1[r] = lerp4(v2[r], v3[r], wx1);
        }
        const float4 s00 = lerp4(d0[0],      d0[1],      wy0);
        const float4 s01 = lerp4(d1[0],      d1[1],      wy0);
        const float4 s10 = lerp4(d0[NR - 2], d0[NR - 1], wy1);
        const float4 s11 = lerp4(d1[NR - 2], d1[NR - 1], wy1);

        st_nt4(outp + pw * NCH, max4(max4(s00, s01), max4(s10, s11)));
    }
}

__global__ __launch_bounds__(128) void roi_pool_kernel(
    const float* __restrict__ fm,
    const float* __restrict__ rois,
    float* __restrict__ out)
{
    const int bi = blockIdx.x;          // n*7 + ph
    const int n  = bi / 7;
    const int ph = bi - n * 7;
    const int c  = threadIdx.x * 4;     // 4 channels per thread (float4)

    // ROI box (block-uniform)
    const float x1 = rois[n * 5 + 1];
    const float y1 = rois[n * 5 + 2];
    const float x2 = rois[n * 5 + 3];
    const float y2 = rois[n * 5 + 4];
    const float SY = 37.0f / 600.0f;    // (H-1)/IM_H
    const float dx = x2 - x1;
    const float dy = y2 - y1;

    // y samples: j = 2*ph + {0,1}
    const float t0  = (float)(2 * ph)     * (1.0f / 13.0f);
    const float t1  = (float)(2 * ph + 1) * (1.0f / 13.0f);
    const float yy0 = (y1 + t0 * dy) * SY;
    const float yy1 = (y1 + t1 * dy) * SY;
    const float yf0 = floorf(yy0), yf1 = floorf(yy1);
    int a0 = (int)yf0; a0 = min(max(a0, 0), FM_H - 1);
    int a1 = (int)yf1; a1 = min(max(a1, 0), FM_H - 1);
    const int yA0 = a0, yB0 = min(a0 + 1, FM_H - 1);
    const int yA1 = a1, yB1 = min(a1 + 1, FM_H - 1);
    const float wy0 = yy0 - yf0;
    const float wy1 = yy1 - yf1;

    const float* fmc = fm + c;
    const float* rA0 = fmc + (size_t)yA0 * (FM_W * NCH);
    const float* rB0 = fmc + (size_t)yB0 * (FM_W * NCH);
    const float* rA1 = fmc + (size_t)yA1 * (FM_W * NCH);
    const float* rB1 = fmc + (size_t)yB1 * (FM_W * NCH);

    // out[n, ph, pw, c] ; bi*7*NCH == (n*49 + ph*7)*NCH
    float* outp = out + (size_t)bi * (7 * NCH) + c;

    // 0 = same cell (rows {A0,B0}), 1 = adjacent (share B0==A1), 2 = disjoint
    const int ycs = (yA1 == yA0) ? 0 : ((yA1 == yB0) ? 1 : 2);
    if (ycs == 0)      roi_rows<2>(rA0, rB0, rB0, rB0, wy0, wy1, x1, dx, outp);
    else if (ycs == 1) roi_rows<3>(rA0, rB0, rB1, rB1, wy0, wy1, x1, dx, outp);
    else               roi_rows<4>(rA0, rB0, rA1, rB1, wy0, wy1, x1, dx, outp);
}

extern "C" void kernel_launch(void* const* d_in, const int* in_sizes, int n_in,
                              void* d_out, int out_size, void* d_ws, size_t ws_size,
                              hipStream_t stream) {
    const float* fm   = (const float*)d_in[0];   // (1,38,50,512) f32
    const float* rois = (const float*)d_in[1];   // (512,5) f32
    float* out = (float*)d_out;                  // (1,512,7,7,512) f32

    const int N = in_sizes[1] / 5;               // 512 rois
    const int blocks = N * 7;                    // one block per (roi, ph)
    roi_pool_kernel<<<blocks, NCH / 4, 0, stream>>>(fm, rois, out);
}

// Round 3
// 88.956 us; speedup vs baseline: 1.0151x; 1.0151x over previous
//
#include <hip/hip_runtime.h>

// RoiPoolingConv: crop_and_resize (bilinear, 14x14 grid) + 2x2 max pool
// fm: (38,50,512) f32; rois: (512,5) f32 [batch, x1, y1, x2, y2]
// out[n,ph,pw,c] = max over (jy,ix in {0,1}) of bilinear sample (2ph+jy, 2pw+ix)
//
// R9 = revert to R6, the best-measured variant (88.1/88.2 us across two
// sessions). R7 (row-dedup sliding window) and R8 (branch-free wide loads)
// both proved the kernel term is minor: the timed graph is dominated by the
// harness's 268 MB re-poison fills (~45 us, at memset roofline) + output
// poison (~9 us); the kernel itself sits near its 51.4 MB write floor
// (~8-10 us). Keep one block per (n,ph,pw): max scheduling parallelism,
// all loads independent, col/row dedup via block-uniform case switches.

#define FM_H 38
#define FM_W 50
#define NCH  512
#define NPP  49   // 7*7

typedef float v4f __attribute__((ext_vector_type(4)));

__device__ __forceinline__ float4 lerp4(const float4 a, const float4 b, const float w) {
    const float iw = 1.0f - w;
    return make_float4(a.x * iw + b.x * w,
                       a.y * iw + b.y * w,
                       a.z * iw + b.z * w,
                       a.w * iw + b.w * w);
}

__device__ __forceinline__ float4 max4(const float4 a, const float4 b) {
    return make_float4(fmaxf(a.x, b.x), fmaxf(a.y, b.y),
                       fmaxf(a.z, b.z), fmaxf(a.w, b.w));
}

#define LD4(p) (*(const float4*)(p))

__device__ __forceinline__ void st_nt4(float* p, const float4 v) {
    v4f vv;
    vv.x = v.x; vv.y = v.y; vv.z = v.z; vv.w = v.w;
    __builtin_nontemporal_store(vv, (v4f*)p);
}

__global__ __launch_bounds__(128) void roi_pool_kernel(
    const float* __restrict__ fm,
    const float* __restrict__ rois,
    float* __restrict__ out)
{
    const int bi = blockIdx.x;          // n*49 + ph*7 + pw
    const int n  = bi / NPP;
    const int r  = bi - n * NPP;
    const int ph = r / 7;
    const int pw = r - ph * 7;
    const int c  = threadIdx.x * 4;     // 4 channels per thread (float4)

    // ROI box (block-uniform). Combined scale: (v/IM) * (dim-1).
    const float x1 = rois[n * 5 + 1];
    const float y1 = rois[n * 5 + 2];
    const float x2 = rois[n * 5 + 3];
    const float y2 = rois[n * 5 + 4];
    const float SX = 49.0f / 800.0f;    // (W-1)/IM_W
    const float SY = 37.0f / 600.0f;    // (H-1)/IM_H

    // --- x samples: i = 2*pw + {0,1} ---
    int   xA0, xB0, xA1, xB1;
    float wx0, wx1;
    {
        const float t0 = (float)(2 * pw)     * (1.0f / 13.0f);
        const float t1 = (float)(2 * pw + 1) * (1.0f / 13.0f);
        const float dx = x2 - x1;
        const float xx0 = (x1 + t0 * dx) * SX;
        const float xx1 = (x1 + t1 * dx) * SX;
        const float xf0 = floorf(xx0), xf1 = floorf(xx1);
        int a0 = (int)xf0; a0 = min(max(a0, 0), FM_W - 1);
        int a1 = (int)xf1; a1 = min(max(a1, 0), FM_W - 1);
        xA0 = a0; xB0 = min(a0 + 1, FM_W - 1);
        xA1 = a1; xB1 = min(a1 + 1, FM_W - 1);
        wx0 = xx0 - xf0;                 // weights from UNclipped floor
        wx1 = xx1 - xf1;
    }
    // --- y samples: j = 2*ph + {0,1} ---
    int   yA0, yB0, yA1, yB1;
    float wy0, wy1;
    {
        const float t0 = (float)(2 * ph)     * (1.0f / 13.0f);
        const float t1 = (float)(2 * ph + 1) * (1.0f / 13.0f);
        const float dy = y2 - y1;
        const float yy0 = (y1 + t0 * dy) * SY;
        const float yy1 = (y1 + t1 * dy) * SY;
        const float yf0 = floorf(yy0), yf1 = floorf(yy1);
        int a0 = (int)yf0; a0 = min(max(a0, 0), FM_H - 1);
        int a1 = (int)yf1; a1 = min(max(a1, 0), FM_H - 1);
        yA0 = a0; yB0 = min(a0 + 1, FM_H - 1);
        yA1 = a1; yB1 = min(a1 + 1, FM_H - 1);
        wy0 = yy0 - yf0;
        wy1 = yy1 - yf1;
    }

    // Case per axis (block-uniform): 0 = same cell, 1 = adjacent (share one
    // corner), 2 = disjoint. Note xA1==xA0 implies xB1==xB0.
    const int xcs = (xA1 == xA0) ? 0 : ((xA1 == xB0) ? 1 : 2);
    const int ycs = (yA1 == yA0) ? 0 : ((yA1 == yB0) ? 1 : 2);

    const float* fmc = fm + c;

    // x-interpolate one fm row at both sample columns, with col dedup.
    auto interpX = [&](int row, float4& t0, float4& t1) {
        const float* bp = fmc + (size_t)row * (FM_W * NCH);
        if (xcs == 0) {
            const float4 v0 = LD4(bp + xA0 * NCH);
            const float4 v1 = LD4(bp + xB0 * NCH);
            t0 = lerp4(v0, v1, wx0);
            t1 = lerp4(v0, v1, wx1);
        } else if (xcs == 1) {
            const float4 v0 = LD4(bp + xA0 * NCH);
            const float4 v1 = LD4(bp + xB0 * NCH);   // == xA1
            const float4 v2 = LD4(bp + xB1 * NCH);
            t0 = lerp4(v0, v1, wx0);
            t1 = lerp4(v1, v2, wx1);
        } else {
            const float4 v0 = LD4(bp + xA0 * NCH);
            const float4 v1 = LD4(bp + xB0 * NCH);
            const float4 v2 = LD4(bp + xA1 * NCH);
            const float4 v3 = LD4(bp + xB1 * NCH);
            t0 = lerp4(v0, v1, wx0);
            t1 = lerp4(v2, v3, wx1);
        }
    };

    float4 best;
    if (ycs == 0) {
        // rows {yA0, yB0}; both y-samples use the same row pair
        float4 a0, a1, b0, b1;
        interpX(yA0, a0, a1);
        interpX(yB0, b0, b1);
        const float4 s00 = lerp4(a0, b0, wy0);
        const float4 s01 = lerp4(a1, b1, wy0);
        const float4 s10 = lerp4(a0, b0, wy1);
        const float4 s11 = lerp4(a1, b1, wy1);
        best = max4(max4(s00, s01), max4(s10, s11));
    } else if (ycs == 1) {
        // rows {yA0, yB0==yA1, yB1}
        float4 a0, a1, b0, b1, e0, e1;
        interpX(yA0, a0, a1);
        interpX(yB0, b0, b1);
        interpX(yB1, e0, e1);
        const float4 s00 = lerp4(a0, b0, wy0);
        const float4 s01 = lerp4(a1, b1, wy0);
        const float4 s10 = lerp4(b0, e0, wy1);
        const float4 s11 = lerp4(b1, e1, wy1);
        best = max4(max4(s00, s01), max4(s10, s11));
    } else {
        // 4 distinct rows
        float4 a0, a1, b0, b1, d0, d1, e0, e1;
        interpX(yA0, a0, a1);
        interpX(yB0, b0, b1);
        interpX(yA1, d0, d1);
        interpX(yB1, e0, e1);
        const float4 s00 = lerp4(a0, b0, wy0);
        const float4 s01 = lerp4(a1, b1, wy0);
        const float4 s10 = lerp4(d0, e0, wy1);
        const float4 s11 = lerp4(d1, e1, wy1);
        best = max4(max4(s00, s01), max4(s10, s11));
    }

    // Full-line vector non-temporal store: 64 lanes x 16 B = 1024 B contiguous.
    st_nt4(out + (size_t)bi * NCH + c, best);
}

extern "C" void kernel_launch(void* const* d_in, const int* in_sizes, int n_in,
                              void* d_out, int out_size, void* d_ws, size_t ws_size,
                              hipStream_t stream) {
    const float* fm   = (const float*)d_in[0];   // (1,38,50,512) f32
    const float* rois = (const float*)d_in[1];   // (512,5) f32
    float* out = (float*)d_out;                  // (1,512,7,7,512) f32

    const int N = in_sizes[1] / 5;               // 512 rois
    const int blocks = N * NPP;                  // one block per (roi, ph, pw)
    roi_pool_kernel<<<blocks, NCH / 4, 0, stream>>>(fm, rois, out);
}